// Round 1
// baseline (164.601 us; speedup 1.0000x reference)
//
#include <hip/hip_runtime.h>
#include <hip/hip_bf16.h>
#include <cstdint>

// TT-linear: y[4096,4096] = x[4096,1024] @ W[1024,4096] + bias
// W reconstructed from TT cores (cheap: ~0.2 GFLOP) into B^T bf16 layout,
// then bf16 MFMA GEMM (m97-style: 128x128 tile, BK=64, global_load_lds w16).

typedef __bf16 bf16x8 __attribute__((ext_vector_type(8)));
typedef float f32x4 __attribute__((ext_vector_type(4)));

__device__ __forceinline__ void g2lds16(const void* g, void* l) {
    __builtin_amdgcn_global_load_lds(
        (const __attribute__((address_space(1))) void*)g,
        (__attribute__((address_space(3))) void*)l,
        16, 0, 0);
}

// ---------------------------------------------------------------- x -> bf16
__global__ void f32_to_bf16(const float* __restrict__ x, __bf16* __restrict__ y) {
    int i = (blockIdx.x * blockDim.x + threadIdx.x) * 8;
    float4 a = *(const float4*)(x + i);
    float4 b = *(const float4*)(x + i + 4);
    bf16x8 o;
    o[0] = (__bf16)a.x; o[1] = (__bf16)a.y; o[2] = (__bf16)a.z; o[3] = (__bf16)a.w;
    o[4] = (__bf16)b.x; o[5] = (__bf16)b.y; o[6] = (__bf16)b.z; o[7] = (__bf16)b.w;
    *(bf16x8*)(y + i) = o;
}

// ------------------------------------------------- W^T reconstruction (bf16)
// Wt[n][k] = sum_{r1,r2,r3} c0[m1,n1,r1] c1[r1,m2,n2,r2] c2[r2,m3,n3,r3] c3[r3,m4,n4]
// k = ((m1*8+m2)*4+m3)*4+m4 ; n = ((n1*8+n2)*8+n3)*8+n4
// One block (64 thr) per (m1,n1,m2,n2). Staged in fp32, rounded once to bf16.
__global__ void build_wt(const float* __restrict__ c0, const float* __restrict__ c1,
                         const float* __restrict__ c2, const float* __restrict__ c3,
                         __bf16* __restrict__ wt) {
    __shared__ float t12[16];        // [r2]
    __shared__ float t123[4 * 8 * 16]; // [m3][n3][r3]
    const int b = blockIdx.x;
    const int m1 = b >> 9, n1 = (b >> 6) & 7, m2 = (b >> 3) & 7, n2 = b & 7;
    const int tid = threadIdx.x;
    if (tid < 16) {
        const int r2 = tid;
        float s = 0.f;
        #pragma unroll
        for (int r1 = 0; r1 < 16; ++r1)
            s += c0[(m1 * 8 + n1) * 16 + r1] * c1[((r1 * 8 + m2) * 8 + n2) * 16 + r2];
        t12[r2] = s;
    }
    __syncthreads();
    #pragma unroll
    for (int idx = tid; idx < 512; idx += 64) {
        const int m3 = idx >> 7, n3 = (idx >> 4) & 7, r3 = idx & 15;
        float s = 0.f;
        #pragma unroll
        for (int r2 = 0; r2 < 16; ++r2)
            s += t12[r2] * c2[((r2 * 4 + m3) * 8 + n3) * 16 + r3];
        t123[idx] = s;
    }
    __syncthreads();
    #pragma unroll
    for (int idx = tid; idx < 1024; idx += 64) {
        const int m3 = idx >> 8, m4 = (idx >> 6) & 3, n3 = (idx >> 3) & 7, n4 = idx & 7;
        float s = 0.f;
        #pragma unroll
        for (int r3 = 0; r3 < 16; ++r3)
            s += t123[(m3 * 8 + n3) * 16 + r3] * c3[(r3 * 4 + m4) * 8 + n4];
        const int k = ((m1 * 8 + m2) * 4 + m3) * 4 + m4;
        const int n = ((n1 * 8 + n2) * 8 + n3) * 8 + n4;
        wt[n * 1024 + k] = (__bf16)s;
    }
}

// -------------------------------------------------------------- GEMM + bias
// C[4096,4096] f32 = A[4096,1024] bf16 @ Bt[4096,1024]^T bf16 + bias
// 128x128 block tile, BK=64, 256 thr = 4 waves (2x2), each wave 4x4 MFMA 16x16x32.
__global__ __launch_bounds__(256) void tt_gemm(
    const __bf16* __restrict__ A, const __bf16* __restrict__ B,
    const float* __restrict__ bias, float* __restrict__ C) {
    constexpr int K = 1024, N = 4096;
    __shared__ __bf16 sA[128 * 64];
    __shared__ __bf16 sB[128 * 64];
    const int t = threadIdx.x;
    const int lane = t & 63;
    const int wave = t >> 6;
    const int wm = (wave >> 1) * 64;   // wave row origin in block tile
    const int wn = (wave & 1) * 64;    // wave col origin
    const int bm = (blockIdx.x >> 5) * 128;
    const int bn = (blockIdx.x & 31) * 128;
    const int l15 = lane & 15, lh = lane >> 4;

    f32x4 acc[4][4] = {};

    for (int k0 = 0; k0 < K; k0 += 64) {
        __syncthreads();  // prior tile's ds_reads done before overwrite
        #pragma unroll
        for (int i = 0; i < 4; ++i) {
            const int c = t + i * 256;          // 16B chunk id within tile
            const int r = c >> 3;               // tile row (0..127)
            const int col = (c & 7) * 8;        // k-col start (elems)
            g2lds16(A + (size_t)(bm + r) * K + k0 + col, (char*)sA + (size_t)c * 16);
            g2lds16(B + (size_t)(bn + r) * K + k0 + col, (char*)sB + (size_t)c * 16);
        }
        asm volatile("s_waitcnt vmcnt(0)" ::: "memory");
        __syncthreads();
        #pragma unroll
        for (int kk = 0; kk < 2; ++kk) {
            bf16x8 af[4], bfr[4];
            #pragma unroll
            for (int mi = 0; mi < 4; ++mi)
                af[mi] = *(const bf16x8*)&sA[(wm + mi * 16 + l15) * 64 + kk * 32 + lh * 8];
            #pragma unroll
            for (int ni = 0; ni < 4; ++ni)
                bfr[ni] = *(const bf16x8*)&sB[(wn + ni * 16 + l15) * 64 + kk * 32 + lh * 8];
            #pragma unroll
            for (int mi = 0; mi < 4; ++mi)
                #pragma unroll
                for (int ni = 0; ni < 4; ++ni)
                    acc[mi][ni] = __builtin_amdgcn_mfma_f32_16x16x32_bf16(
                        af[mi], bfr[ni], acc[mi][ni], 0, 0, 0);
        }
    }

    // epilogue: C/D layout col=lane&15, row=(lane>>4)*4+reg  (m89-verified)
    #pragma unroll
    for (int ni = 0; ni < 4; ++ni) {
        const int col = bn + wn + ni * 16 + l15;
        const float bv = bias[col];
        #pragma unroll
        for (int mi = 0; mi < 4; ++mi) {
            const int row0 = bm + wm + mi * 16 + lh * 4;
            const f32x4 v = acc[mi][ni];
            #pragma unroll
            for (int r = 0; r < 4; ++r)
                C[(size_t)(row0 + r) * N + col] = v[r] + bv;
        }
    }
}

extern "C" void kernel_launch(void* const* d_in, const int* in_sizes, int n_in,
                              void* d_out, int out_size, void* d_ws, size_t ws_size,
                              hipStream_t stream) {
    const float* x    = (const float*)d_in[0];
    const float* c0   = (const float*)d_in[1];
    const float* c1   = (const float*)d_in[2];
    const float* c2   = (const float*)d_in[3];
    const float* c3   = (const float*)d_in[4];
    const float* bias = (const float*)d_in[5];
    float* out = (float*)d_out;

    __bf16* xb = (__bf16*)d_ws;                    // 4096*1024 bf16 = 8.39 MB
    __bf16* wt = xb + (size_t)4096 * 1024;         // 4096*1024 bf16 = 8.39 MB

    f32_to_bf16<<<2048, 256, 0, stream>>>(x, xb);                 // 4096*1024/8 per-thread=8
    build_wt<<<4096, 64, 0, stream>>>(c0, c1, c2, c3, wt);
    tt_gemm<<<1024, 256, 0, stream>>>(xb, wt, bias, out);
}

// Round 3
// 142.075 us; speedup vs baseline: 1.1586x; 1.1586x over previous
//
#include <hip/hip_runtime.h>
#include <hip/hip_bf16.h>
#include <cstdint>

// TT-linear: y[4096,4096] = x[4096,1024] @ W[1024,4096] + bias
// Kernel 1 (prep): fused x->bf16 convert + W^T reconstruction from TT cores.
// Kernel 2 (tt_gemm): bf16 MFMA GEMM, 128x128 tile, BK=64, global_load_lds w16,
//                     XOR-swizzled LDS (bank-conflict-free fragment reads).

typedef __bf16 bf16x8 __attribute__((ext_vector_type(8)));
typedef float f32x4 __attribute__((ext_vector_type(4)));

__device__ __forceinline__ void g2lds16(const void* g, void* l) {
    __builtin_amdgcn_global_load_lds(
        (const __attribute__((address_space(1))) void*)g,
        (__attribute__((address_space(3))) void*)l,
        16, 0, 0);
}

// --------------------------------------------------------------------- prep
// blocks [0,2048): convert x (4096x1024 f32) -> xb bf16, 8 elems/thread
// blocks [2048,3072): build wt[n][k] bf16; 4 groups (m1,n1,m2,n2) per block,
//   one wave per group; lane = local n (64 values), 16 k-values per lane
//   accumulated in registers, stored as two contiguous 16B bf16x8 stores.
__global__ __launch_bounds__(256) void prep(
    const float* __restrict__ x, __bf16* __restrict__ xb,
    const float* __restrict__ c0, const float* __restrict__ c1,
    const float* __restrict__ c2, const float* __restrict__ c3,
    __bf16* __restrict__ wt) {
    const int b = blockIdx.x;
    const int t = threadIdx.x;
    if (b < 2048) {
        const int i = (b * 256 + t) * 8;
        float4 a0 = *(const float4*)(x + i);
        float4 a1 = *(const float4*)(x + i + 4);
        bf16x8 o;
        o[0] = (__bf16)a0.x; o[1] = (__bf16)a0.y; o[2] = (__bf16)a0.z; o[3] = (__bf16)a0.w;
        o[4] = (__bf16)a1.x; o[5] = (__bf16)a1.y; o[6] = (__bf16)a1.z; o[7] = (__bf16)a1.w;
        *(bf16x8*)(xb + i) = o;
        return;
    }
    __shared__ float t12[4][16];     // [wave][r2]
    __shared__ float t123[4][512];   // [wave][m3*8+n3][r3]
    __shared__ float c3s[512];       // [(r3*4+m4)*8+n4]
    // stage c3 (512 floats) once per block — 256 threads, 2 elems each
    #pragma unroll
    for (int i = t; i < 512; i += 256) c3s[i] = c3[i];
    const int s = t >> 6;            // wave id = group within block
    const int lane = t & 63;
    const int g = (b - 2048) * 4 + s;          // group id 0..4095
    const int m1 = g >> 9, n1 = (g >> 6) & 7, m2 = (g >> 3) & 7, n2 = g & 7;
    __syncthreads();
    if (lane < 16) {
        const int r2 = lane;
        float sum = 0.f;
        #pragma unroll
        for (int r1 = 0; r1 < 16; ++r1)
            sum += c0[(m1 * 8 + n1) * 16 + r1] * c1[((r1 * 8 + m2) * 8 + n2) * 16 + r2];
        t12[s][r2] = sum;
    }
    __syncthreads();
    #pragma unroll
    for (int idx = lane; idx < 512; idx += 64) {
        const int m3 = idx >> 7, n3 = (idx >> 4) & 7, r3 = idx & 15;
        float sum = 0.f;
        #pragma unroll
        for (int r2 = 0; r2 < 16; ++r2)
            sum += t12[s][r2] * c2[((r2 * 4 + m3) * 8 + n3) * 16 + r3];
        t123[s][(m3 * 8 + n3) * 16 + r3] = sum;
    }
    __syncthreads();
    // lane owns one n; compute all 16 k = m3*4+m4 in registers
    const int n3 = lane >> 3, n4 = lane & 7;
    const int n = ((n1 * 8 + n2) * 8 + n3) * 8 + n4;
    const int kbase = (m1 * 8 + m2) * 16;
    float v[16];
    #pragma unroll
    for (int e = 0; e < 16; ++e) v[e] = 0.f;
    #pragma unroll
    for (int m3 = 0; m3 < 4; ++m3) {
        #pragma unroll
        for (int r3 = 0; r3 < 16; ++r3) {
            const float tv = t123[s][(m3 * 8 + n3) * 16 + r3];
            #pragma unroll
            for (int m4 = 0; m4 < 4; ++m4)
                v[m3 * 4 + m4] += tv * c3s[(r3 * 4 + m4) * 8 + n4];
        }
    }
    bf16x8 lo, hi;
    #pragma unroll
    for (int e = 0; e < 8; ++e) { lo[e] = (__bf16)v[e]; hi[e] = (__bf16)v[8 + e]; }
    *(bf16x8*)(wt + (size_t)n * 1024 + kbase)     = lo;
    *(bf16x8*)(wt + (size_t)n * 1024 + kbase + 8) = hi;
}

// -------------------------------------------------------------- GEMM + bias
// C[4096,4096] f32 = A[4096,1024] bf16 @ Bt[4096,1024]^T bf16 + bias
// 128x128 block tile, BK=64, 4 waves (2x2), each wave 4x4 of 16x16x32 MFMA.
// LDS XOR swizzle: physical 16B chunk pc of row r holds logical chunk pc^(r&7).
// Staging fetches the swizzled global chunk so global_load_lds stays contiguous;
// fragment reads then hit all 32 banks (8 addrs/bank = b128 minimum, 0 conflicts).
__global__ __launch_bounds__(256) void tt_gemm(
    const __bf16* __restrict__ A, const __bf16* __restrict__ B,
    const float* __restrict__ bias, float* __restrict__ C) {
    constexpr int K = 1024, N = 4096;
    __shared__ __bf16 sA[128 * 64];
    __shared__ __bf16 sB[128 * 64];
    const int t = threadIdx.x;
    const int lane = t & 63;
    const int wave = t >> 6;
    const int wm = (wave >> 1) * 64;
    const int wn = (wave & 1) * 64;
    // XCD-aware mapping: xcd = blk%8 owns a 4-wide bn band, sweeps all bm
    const int xcd = blockIdx.x & 7;
    const int lid = blockIdx.x >> 3;           // 0..127
    const int bm = (lid & 31) * 128;
    const int bn = (xcd * 4 + (lid >> 5)) * 128;
    const int l15 = lane & 15, lh = lane >> 4;
    const int swz = l15 & 7;

    f32x4 acc[4][4] = {};

    for (int k0 = 0; k0 < K; k0 += 64) {
        __syncthreads();  // prior tile's ds_reads done before overwrite
        #pragma unroll
        for (int i = 0; i < 4; ++i) {
            const int c = t + i * 256;          // physical 16B chunk id
            const int r = c >> 3;               // tile row (0..127)
            const int gc = (c & 7) ^ (r & 7);   // logical (global) chunk
            g2lds16(A + (size_t)(bm + r) * K + k0 + gc * 8, (char*)sA + (size_t)c * 16);
            g2lds16(B + (size_t)(bn + r) * K + k0 + gc * 8, (char*)sB + (size_t)c * 16);
        }
        asm volatile("s_waitcnt vmcnt(0)" ::: "memory");
        __syncthreads();
        #pragma unroll
        for (int kk = 0; kk < 2; ++kk) {
            const int coff = ((kk * 4 + lh) ^ swz) * 16;  // swizzled byte offset in row
            bf16x8 af[4], bfr[4];
            #pragma unroll
            for (int mi = 0; mi < 4; ++mi)
                af[mi] = *(const bf16x8*)((const char*)sA + (size_t)(wm + mi * 16 + l15) * 128 + coff);
            #pragma unroll
            for (int ni = 0; ni < 4; ++ni)
                bfr[ni] = *(const bf16x8*)((const char*)sB + (size_t)(wn + ni * 16 + l15) * 128 + coff);
            #pragma unroll
            for (int mi = 0; mi < 4; ++mi)
                #pragma unroll
                for (int ni = 0; ni < 4; ++ni)
                    acc[mi][ni] = __builtin_amdgcn_mfma_f32_16x16x32_bf16(
                        af[mi], bfr[ni], acc[mi][ni], 0, 0, 0);
        }
    }

    // epilogue: C/D layout col=lane&15, row=(lane>>4)*4+reg (m89-verified)
    #pragma unroll
    for (int ni = 0; ni < 4; ++ni) {
        const int col = bn + wn + ni * 16 + l15;
        const float bv = bias[col];
        #pragma unroll
        for (int mi = 0; mi < 4; ++mi) {
            const int row0 = bm + wm + mi * 16 + lh * 4;
            const f32x4 v = acc[mi][ni];
            #pragma unroll
            for (int r = 0; r < 4; ++r)
                C[(size_t)(row0 + r) * N + col] = v[r] + bv;
        }
    }
}

extern "C" void kernel_launch(void* const* d_in, const int* in_sizes, int n_in,
                              void* d_out, int out_size, void* d_ws, size_t ws_size,
                              hipStream_t stream) {
    const float* x    = (const float*)d_in[0];
    const float* c0   = (const float*)d_in[1];
    const float* c1   = (const float*)d_in[2];
    const float* c2   = (const float*)d_in[3];
    const float* c3   = (const float*)d_in[4];
    const float* bias = (const float*)d_in[5];
    float* out = (float*)d_out;

    __bf16* xb = (__bf16*)d_ws;                    // 4096*1024 bf16 = 8.39 MB
    __bf16* wt = xb + (size_t)4096 * 1024;         // 4096*1024 bf16 = 8.39 MB

    prep<<<3072, 256, 0, stream>>>(x, xb, c0, c1, c2, c3, wt);
    tt_gemm<<<1024, 256, 0, stream>>>(xb, wt, bias, out);
}